// Round 5
// baseline (238.835 us; speedup 1.0000x reference)
//
#include <hip/hip_runtime.h>

typedef __attribute__((ext_vector_type(8))) short bfrag;
typedef __attribute__((ext_vector_type(4))) float f32x4;

#define XS4 331776   // 24^4
#define XS3 13824    // 24^3
#define XS2 576      // 24^2

#define WS_ZERO   86016            // 64B zero scratch after wfrag
#define WS_XS     86080            // xsplit base (16B aligned)
#define XS_HALF_B 5308416          // XS4*16 bytes between hi and lo halves
#define WS_NEED   42553408ull      // 86080 + 4*2*XS4*16
#define NSITE     1260
#define NSITE_PAD 1280
#define LDS_LO    20480            // 1280*16

// ---------------- combined pre-kernel: wsplit (blocks 0..83) + xsplit -------
// wfrag: u16 [cs=ch*2+s][tau 0..83][co 0..15][ci8]; taus 81..83 zero.
// xs:    u16 [bc=b*2+ch][half][s4][ci8]
__global__ void presplit_kernel(const float* __restrict__ x,
                                const float* __restrict__ w,
                                unsigned int* __restrict__ ws,
                                unsigned short* __restrict__ xs) {
    int bid = blockIdx.x;
    int tid = threadIdx.x;
    if (bid < 84) {
        // ---- weight split ----
        int e = bid * 256 + tid;                  // 0 .. 21503
        int ci2 = e & 3;
        int co  = (e >> 2) & 15;
        int t84 = e >> 6;
        int tau = t84 % 84;
        int cs  = t84 / 84;
        int ch  = cs >> 1;
        int s   = cs & 1;
        unsigned int outv = 0u;
        if (tau < 81) {
            unsigned int half[2];
#pragma unroll
            for (int q = 0; q < 2; ++q) {
                int ci = ch * 8 + ci2 * 2 + q;
                union { float f; unsigned u; } v;
                v.f = w[(co * 16 + ci) * 81 + tau];
                unsigned hi = v.u & 0xFFFF0000u;
                union { unsigned u; float f; } hv; hv.u = hi;
                union { float f; unsigned u; } rv; rv.f = v.f - hv.f;
                unsigned lo = rv.u & 0xFFFF0000u;
                half[q] = (s == 0) ? hi : lo;
            }
            outv = (half[0] >> 16) | (half[1] & 0xFFFF0000u);
        }
        ws[e] = outv;
        if (e < 16) ws[(WS_ZERO / 4) + e] = 0u;   // 64B zero scratch
    } else {
        // ---- x split ----
        int xb = bid - 84;                         // 0 .. 5183
        int s4 = (xb % 1296) * 256 + tid;          // 0 .. 331775
        int bc = xb / 1296;                        // b*2+ch
        const float* xp = x + (size_t)(bc * 8) * XS4 + s4;
        unsigned hib[8], lob[8];
#pragma unroll
        for (int c = 0; c < 8; ++c) {
            union { float f; unsigned u; } v;
            v.f = xp[(size_t)c * XS4];
            unsigned hi = v.u & 0xFFFF0000u;
            union { unsigned u; float f; } hv; hv.u = hi;
            union { float f; unsigned u; } rv; rv.f = v.f - hv.f;
            hib[c] = hi;
            lob[c] = rv.u & 0xFFFF0000u;
        }
        uint4 ph, pl;
        ph.x = (hib[0] >> 16) | (hib[1] & 0xFFFF0000u);
        ph.y = (hib[2] >> 16) | (hib[3] & 0xFFFF0000u);
        ph.z = (hib[4] >> 16) | (hib[5] & 0xFFFF0000u);
        ph.w = (hib[6] >> 16) | (hib[7] & 0xFFFF0000u);
        pl.x = (lob[0] >> 16) | (lob[1] & 0xFFFF0000u);
        pl.y = (lob[2] >> 16) | (lob[3] & 0xFFFF0000u);
        pl.z = (lob[4] >> 16) | (lob[5] & 0xFFFF0000u);
        pl.w = (lob[6] >> 16) | (lob[7] & 0xFFFF0000u);
        *(uint4*)(xs + ((size_t)(bc * 2 + 0) * XS4 + s4) * 8) = ph;
        *(uint4*)(xs + ((size_t)(bc * 2 + 1) * XS4 + s4) * 8) = pl;
    }
}

// ---------------- main kernel v3: dd-innermost LDS layout (conflict-free) ---
// LDS slot(p,dd,tt) = p*140 + tt*10 + dd  -> dd stride 16B, tt stride 160B.
// 16-lane k-group reads: dwords {t_i*40 + d_i*4} mod 32 tile all banks exactly.
__global__ __launch_bounds__(192, 3)
void conv4d_mfma_v3(const unsigned short* __restrict__ xs,
                    const unsigned short* __restrict__ wfrag,
                    const char* __restrict__ zptr,
                    const float* __restrict__ bias,
                    float* __restrict__ out) {
    __shared__ __align__(16) unsigned short xhl[2 * NSITE_PAD * 8];  // 40960 B

    const int tid  = threadIdx.x;
    const int l    = tid & 63;
    const int wv   = tid >> 6;

    int bid = blockIdx.x;
    const int b    = bid / 3456;
    int r          = bid % 3456;
    const int h    = r / 144;
    r              = r % 144;
    const int w0   = r / 6;
    const int seg  = r % 6;
    const int dbase = (seg >> 1) * 8, tbase = (seg & 1) * 12;

    const int i_  = l & 15;
    const int tl4 = l >> 4;
    const int d_i = i_ >> 2;
    const int t_i = i_ & 3;
    const int co  = l & 15;

    const int mt0 = wv * 2, mt1 = wv * 2 + 1;
    const int dq0 = mt0 / 3, tq0 = mt0 % 3;
    const int dq1 = mt1 / 3, tq1 = mt1 % 3;
    // byte offsets in transposed layout: d stride 16B, t stride 160B
    const int la0 = tq0 * 640 + t_i * 160 + dq0 * 64 + d_i * 16;
    const int la1 = tq1 * 640 + t_i * 160 + dq1 * 64 + d_i * 16;

    // hoisted per-lane tap offsets (fully unrolled -> registers)
    int aoffs[21];
#pragma unroll
    for (int g = 0; g < 21; ++g) {
        int tau  = 4 * g + tl4;
        int teff = tau > 80 ? 80 : tau;
        int p    = teff / 9;
        int r9   = teff - p * 9;
        int kd   = r9 / 3;
        int kt   = r9 - kd * 3;
        aoffs[g] = p * 2240 + kt * 160 + kd * 16;
    }

    f32x4 acc0 = {0.f, 0.f, 0.f, 0.f};
    f32x4 acc1 = {0.f, 0.f, 0.f, 0.f};

    const char* xbase = (const char*)&xhl[0];
    const char* xsb   = (const char*)xs;
    const char* wB    = (const char*)wfrag + tl4 * 256 + co * 16;

    for (int ch = 0; ch < 2; ++ch) {
        __syncthreads();

        const unsigned base16 = (unsigned)((b * 2 + ch) * 2) * (unsigned)(XS4 * 16);

        // ---- stage via direct global->LDS DMA, 16B per lane ----
        // slot idx = p*140 + tt*10 + dd
        for (int k = 0; k < 7; ++k) {
            int idx0 = k * 192 + wv * 64;          // wave-uniform
            if (idx0 < NSITE_PAD) {
                int idx = idx0 + l;
                int p  = idx / 140;
                int rr = idx - p * 140;
                int tt = rr / 10;
                int dd = rr - tt * 10;
                int hh = h  + p / 3 - 1;
                int ww = w0 + p % 3 - 1;
                int dp = dbase + dd - 1;
                int tp = tbase + tt - 1;
                bool valid = ((unsigned)hh < 24u) && ((unsigned)ww < 24u) &&
                             ((unsigned)dp < 24u) && ((unsigned)tp < 24u) &&
                             (idx < NSITE);
                const char* gh = zptr;
                const char* gl = zptr;
                if (valid) {
                    unsigned off = base16 +
                        (unsigned)(hh * XS3 + ww * XS2 + dp * 24 + tp) * 16u;
                    gh = xsb + off;
                    gl = gh + XS_HALF_B;
                }
                char* lp = (char*)&xhl[0] + idx * 16;
                __builtin_amdgcn_global_load_lds(
                    (const __attribute__((address_space(1))) void*)gh,
                    (__attribute__((address_space(3))) void*)lp, 16, 0, 0);
                __builtin_amdgcn_global_load_lds(
                    (const __attribute__((address_space(1))) void*)gl,
                    (__attribute__((address_space(3))) void*)(lp + LDS_LO), 16, 0, 0);
            }
        }
        __syncthreads();

        const char* pw = wB + ch * 43008;

#pragma unroll
        for (int g = 0; g < 21; ++g) {
            bfrag whf = *(const bfrag*)(pw + g * 1024);
            bfrag wlf = *(const bfrag*)(pw + g * 1024 + 21504);

            const char* ax = xbase + aoffs[g];
            bfrag xh0 = *(const bfrag*)(ax + la0);
            bfrag xl0 = *(const bfrag*)(ax + la0 + LDS_LO);
            bfrag xh1 = *(const bfrag*)(ax + la1);
            bfrag xl1 = *(const bfrag*)(ax + la1 + LDS_LO);

            __builtin_amdgcn_s_setprio(1);
            acc0 = __builtin_amdgcn_mfma_f32_16x16x32_bf16(xh0, whf, acc0, 0, 0, 0);
            acc1 = __builtin_amdgcn_mfma_f32_16x16x32_bf16(xh1, whf, acc1, 0, 0, 0);
            acc0 = __builtin_amdgcn_mfma_f32_16x16x32_bf16(xh0, wlf, acc0, 0, 0, 0);
            acc1 = __builtin_amdgcn_mfma_f32_16x16x32_bf16(xh1, wlf, acc1, 0, 0, 0);
            acc0 = __builtin_amdgcn_mfma_f32_16x16x32_bf16(xl0, whf, acc0, 0, 0, 0);
            acc1 = __builtin_amdgcn_mfma_f32_16x16x32_bf16(xl1, whf, acc1, 0, 0, 0);
            __builtin_amdgcn_s_setprio(0);
        }
    }

    const float bv = bias[co];
    const int ob = (b * 16 + co) * XS4 + h * XS3 + w0 * XS2;
    {
        int d = dbase + dq0 * 4 + tl4;
        int t = tbase + tq0 * 4;
        float4 v;
        v.x = acc0[0] + bv; v.y = acc0[1] + bv;
        v.z = acc0[2] + bv; v.w = acc0[3] + bv;
        *(float4*)&out[ob + d * 24 + t] = v;
    }
    {
        int d = dbase + dq1 * 4 + tl4;
        int t = tbase + tq1 * 4;
        float4 v;
        v.x = acc1[0] + bv; v.y = acc1[1] + bv;
        v.z = acc1[2] + bv; v.w = acc1[3] + bv;
        *(float4*)&out[ob + d * 24 + t] = v;
    }
}

// ---------------- fallback (in-kernel split, used if ws too small) ----------
__global__ void wsplit_kernel(const float* __restrict__ w,
                              unsigned int* __restrict__ ws) {
    int e = blockIdx.x * 256 + threadIdx.x;
    int ci2 = e & 3;
    int co  = (e >> 2) & 15;
    int t84 = e >> 6;
    int tau = t84 % 84;
    int cs  = t84 / 84;
    int ch  = cs >> 1;
    int s   = cs & 1;
    unsigned int outv = 0u;
    if (tau < 81) {
        unsigned int half[2];
#pragma unroll
        for (int q = 0; q < 2; ++q) {
            int ci = ch * 8 + ci2 * 2 + q;
            union { float f; unsigned u; } v;
            v.f = w[(co * 16 + ci) * 81 + tau];
            unsigned hi = v.u & 0xFFFF0000u;
            union { unsigned u; float f; } hv; hv.u = hi;
            union { float f; unsigned u; } rv; rv.f = v.f - hv.f;
            unsigned lo = rv.u & 0xFFFF0000u;
            half[q] = (s == 0) ? hi : lo;
        }
        outv = (half[0] >> 16) | (half[1] & 0xFFFF0000u);
    }
    ws[e] = outv;
}

__global__ __launch_bounds__(192, 3)
void conv4d_mfma_v1(const float* __restrict__ x,
                    const unsigned short* __restrict__ wfrag,
                    const float* __restrict__ bias,
                    float* __restrict__ out) {
    __shared__ __align__(16) unsigned short xhl[2][1260][8];

    const int tid = threadIdx.x;
    const int l   = tid & 63;

    int bid = blockIdx.x;
    const int b    = bid / 3456;
    int r          = bid % 3456;
    const int h    = r / 144;
    r              = r % 144;
    const int w0   = r / 6;
    const int seg  = r % 6;
    const int dbase = (seg >> 1) * 8, tbase = (seg & 1) * 12;

    const int i_  = l & 15;
    const int tl4 = l >> 4;
    const int d_i = i_ >> 2;
    const int t_i = i_ & 3;
    const int co  = l & 15;

    const int wv  = tid >> 6;
    const int mt0 = wv * 2, mt1 = wv * 2 + 1;
    const int dq0 = mt0 / 3, tq0 = mt0 % 3;
    const int dq1 = mt1 / 3, tq1 = mt1 % 3;
    const int la0 = dq0 * 896 + tq0 * 64 + d_i * 224 + t_i * 16;
    const int la1 = dq1 * 896 + tq1 * 64 + d_i * 224 + t_i * 16;

    f32x4 acc0 = {0.f, 0.f, 0.f, 0.f};
    f32x4 acc1 = {0.f, 0.f, 0.f, 0.f};

    const char* xbase = (const char*)&xhl[0][0][0];
    const char* wB    = (const char*)wfrag + tl4 * 256 + co * 16;

    for (int ch = 0; ch < 2; ++ch) {
        __syncthreads();
        for (int k = 0; k < 7; ++k) {
            int idx = tid + k * 192;
            if (idx < 1260) {
                int p  = idx / 140;
                int rr = idx - p * 140;
                int dd = rr / 14;
                int tt = rr - dd * 14;
                int hh = h  + p / 3 - 1;
                int ww = w0 + p % 3 - 1;
                int dp = dbase + dd - 1;
                int tp = tbase + tt - 1;
                unsigned hib[8], lob[8];
                bool valid = ((unsigned)hh < 24u) && ((unsigned)ww < 24u) &&
                             ((unsigned)dp < 24u) && ((unsigned)tp < 24u);
                if (valid) {
                    int g = b * (16 * XS4) + (ch * 8) * XS4
                          + hh * XS3 + ww * XS2 + dp * 24 + tp;
#pragma unroll
                    for (int c = 0; c < 8; ++c) {
                        union { float f; unsigned u; } v;
                        v.f = x[g + c * XS4];
                        unsigned hi = v.u & 0xFFFF0000u;
                        union { unsigned u; float f; } hv; hv.u = hi;
                        union { float f; unsigned u; } rv2; rv2.f = v.f - hv.f;
                        hib[c] = hi;
                        lob[c] = rv2.u & 0xFFFF0000u;
                    }
                } else {
#pragma unroll
                    for (int c = 0; c < 8; ++c) { hib[c] = 0u; lob[c] = 0u; }
                }
                uint4 ph, pl;
                ph.x = (hib[0] >> 16) | (hib[1] & 0xFFFF0000u);
                ph.y = (hib[2] >> 16) | (hib[3] & 0xFFFF0000u);
                ph.z = (hib[4] >> 16) | (hib[5] & 0xFFFF0000u);
                ph.w = (hib[6] >> 16) | (hib[7] & 0xFFFF0000u);
                pl.x = (lob[0] >> 16) | (lob[1] & 0xFFFF0000u);
                pl.y = (lob[2] >> 16) | (lob[3] & 0xFFFF0000u);
                pl.z = (lob[4] >> 16) | (lob[5] & 0xFFFF0000u);
                pl.w = (lob[6] >> 16) | (lob[7] & 0xFFFF0000u);
                *(uint4*)((char*)&xhl[0][0][0] + idx * 16)         = ph;
                *(uint4*)((char*)&xhl[0][0][0] + 20160 + idx * 16) = pl;
            }
        }
        __syncthreads();

        const char* pw = wB + ch * 43008;
#pragma unroll
        for (int g = 0; g < 21; ++g) {
            bfrag whf = *(const bfrag*)(pw + g * 1024);
            bfrag wlf = *(const bfrag*)(pw + g * 1024 + 21504);

            int tau  = 4 * g + tl4;
            int teff = tau > 80 ? 80 : tau;
            int p    = teff / 9;
            int r9   = teff - p * 9;
            int kd   = r9 / 3;
            int kt   = r9 - kd * 3;
            int aoff = p * 2240 + kd * 224 + kt * 16;

            const char* ax = xbase + aoff;
            bfrag xh0 = *(const bfrag*)(ax + la0);
            bfrag xl0 = *(const bfrag*)(ax + la0 + 20160);
            bfrag xh1 = *(const bfrag*)(ax + la1);
            bfrag xl1 = *(const bfrag*)(ax + la1 + 20160);

            acc0 = __builtin_amdgcn_mfma_f32_16x16x32_bf16(xh0, whf, acc0, 0, 0, 0);
            acc1 = __builtin_amdgcn_mfma_f32_16x16x32_bf16(xh1, whf, acc1, 0, 0, 0);
            acc0 = __builtin_amdgcn_mfma_f32_16x16x32_bf16(xh0, wlf, acc0, 0, 0, 0);
            acc1 = __builtin_amdgcn_mfma_f32_16x16x32_bf16(xh1, wlf, acc1, 0, 0, 0);
            acc0 = __builtin_amdgcn_mfma_f32_16x16x32_bf16(xl0, whf, acc0, 0, 0, 0);
            acc1 = __builtin_amdgcn_mfma_f32_16x16x32_bf16(xl1, whf, acc1, 0, 0, 0);
        }
    }

    const float bv = bias[co];
    const int ob = (b * 16 + co) * XS4 + h * XS3 + w0 * XS2;
    {
        int d = dbase + dq0 * 4 + tl4;
        int t = tbase + tq0 * 4;
        float4 v;
        v.x = acc0[0] + bv; v.y = acc0[1] + bv;
        v.z = acc0[2] + bv; v.w = acc0[3] + bv;
        *(float4*)&out[ob + d * 24 + t] = v;
    }
    {
        int d = dbase + dq1 * 4 + tl4;
        int t = tbase + tq1 * 4;
        float4 v;
        v.x = acc1[0] + bv; v.y = acc1[1] + bv;
        v.z = acc1[2] + bv; v.w = acc1[3] + bv;
        *(float4*)&out[ob + d * 24 + t] = v;
    }
}

extern "C" void kernel_launch(void* const* d_in, const int* in_sizes, int n_in,
                              void* d_out, int out_size, void* d_ws, size_t ws_size,
                              hipStream_t stream) {
    const float* x    = (const float*)d_in[0];
    const float* w    = (const float*)d_in[1];
    const float* bias = (const float*)d_in[2];
    float* out        = (float*)d_out;
    char* ws          = (char*)d_ws;
    unsigned* wfrag   = (unsigned*)ws;

    if (ws_size >= WS_NEED) {
        unsigned short* xsq = (unsigned short*)(ws + WS_XS);
        presplit_kernel<<<84 + 5184, 256, 0, stream>>>(x, w, wfrag, xsq);
        conv4d_mfma_v3<<<6912, 192, 0, stream>>>(
            xsq, (const unsigned short*)wfrag, ws + WS_ZERO, bias, out);
    } else {
        wsplit_kernel<<<84, 256, 0, stream>>>(w, wfrag);
        conv4d_mfma_v1<<<6912, 192, 0, stream>>>(
            x, (const unsigned short*)wfrag, bias, out);
    }
}

// Round 6
// 227.966 us; speedup vs baseline: 1.0477x; 1.0477x over previous
//
#include <hip/hip_runtime.h>

typedef __attribute__((ext_vector_type(8))) short bfrag;
typedef __attribute__((ext_vector_type(4))) float f32x4;

#define XS4 331776   // 24^4
#define XS3 13824    // 24^3
#define XS2 576      // 24^2

#define WS_ZERO   86016            // 64B zero scratch after wfrag
#define WS_XS     86080            // xsplit base (16B aligned)
#define XS_HALF_B 5308416          // XS4*16 bytes between hi and lo halves (v1 path)
#define WS_NEED   42553408ull      // 86080 + 8*XS4*16
#define NSITE2    2340             // 9p * 10dd * 26tt
#define NPAD2     2560             // padded to 10 loads/thread * 256 threads

// ---------------- combined pre-kernel: wsplit (blocks 0..83) + xsplit -------
// wfrag: u16 [cs=ch*2+s][tau 0..83][co 0..15][ci8]; taus 81..83 zero.
// xs:    u16 [(b*2+ch)*2 + s][s4][ci8]   (i.e. chunk index b*4 + ch*2 + s)
__global__ void presplit_kernel(const float* __restrict__ x,
                                const float* __restrict__ w,
                                unsigned int* __restrict__ ws,
                                unsigned short* __restrict__ xs) {
    int bid = blockIdx.x;
    int tid = threadIdx.x;
    if (bid < 84) {
        int e = bid * 256 + tid;                  // 0 .. 21503
        int ci2 = e & 3;
        int co  = (e >> 2) & 15;
        int t84 = e >> 6;
        int tau = t84 % 84;
        int cs  = t84 / 84;
        int ch  = cs >> 1;
        int s   = cs & 1;
        unsigned int outv = 0u;
        if (tau < 81) {
            unsigned int half[2];
#pragma unroll
            for (int q = 0; q < 2; ++q) {
                int ci = ch * 8 + ci2 * 2 + q;
                union { float f; unsigned u; } v;
                v.f = w[(co * 16 + ci) * 81 + tau];
                unsigned hi = v.u & 0xFFFF0000u;
                union { unsigned u; float f; } hv; hv.u = hi;
                union { float f; unsigned u; } rv; rv.f = v.f - hv.f;
                unsigned lo = rv.u & 0xFFFF0000u;
                half[q] = (s == 0) ? hi : lo;
            }
            outv = (half[0] >> 16) | (half[1] & 0xFFFF0000u);
        }
        ws[e] = outv;
        if (e < 16) ws[(WS_ZERO / 4) + e] = 0u;   // 64B zero scratch
    } else {
        int xb = bid - 84;                         // 0 .. 5183
        int s4 = (xb % 1296) * 256 + tid;          // 0 .. 331775
        int bc = xb / 1296;                        // b*2+ch
        const float* xp = x + (size_t)(bc * 8) * XS4 + s4;
        unsigned hib[8], lob[8];
#pragma unroll
        for (int c = 0; c < 8; ++c) {
            union { float f; unsigned u; } v;
            v.f = xp[(size_t)c * XS4];
            unsigned hi = v.u & 0xFFFF0000u;
            union { unsigned u; float f; } hv; hv.u = hi;
            union { float f; unsigned u; } rv; rv.f = v.f - hv.f;
            hib[c] = hi;
            lob[c] = rv.u & 0xFFFF0000u;
        }
        uint4 ph, pl;
        ph.x = (hib[0] >> 16) | (hib[1] & 0xFFFF0000u);
        ph.y = (hib[2] >> 16) | (hib[3] & 0xFFFF0000u);
        ph.z = (hib[4] >> 16) | (hib[5] & 0xFFFF0000u);
        ph.w = (hib[6] >> 16) | (hib[7] & 0xFFFF0000u);
        pl.x = (lob[0] >> 16) | (lob[1] & 0xFFFF0000u);
        pl.y = (lob[2] >> 16) | (lob[3] & 0xFFFF0000u);
        pl.z = (lob[4] >> 16) | (lob[5] & 0xFFFF0000u);
        pl.w = (lob[6] >> 16) | (lob[7] & 0xFFFF0000u);
        *(uint4*)(xs + ((size_t)(bc * 2 + 0) * XS4 + s4) * 8) = ph;
        *(uint4*)(xs + ((size_t)(bc * 2 + 1) * XS4 + s4) * 8) = pl;
    }
}

// ---------------- main kernel v4: 4-phase double-buffered pipeline ----------
// block = (b, h, w, dseg): 3456 blocks, 256 threads (4 waves), 8x24 outputs.
// Phases k=0..3: chunk = b*4+k = (ch = k>>1, s = k&1). Stage(k+1) issued
// BEFORE compute(k) so global->LDS latency hides under the MFMA burst;
// __syncthreads() at the next phase boundary finds loads already complete.
__global__ __launch_bounds__(256, 2)
void conv4d_pipe(const unsigned short* __restrict__ xs,
                 const unsigned short* __restrict__ wfrag,
                 const char* __restrict__ zptr,
                 const float* __restrict__ bias,
                 float* __restrict__ out) {
    __shared__ __align__(16) unsigned short xbuf[2][NPAD2 * 8];  // 81920 B

    const int tid = threadIdx.x;
    const int l   = tid & 63;
    const int wv  = tid >> 6;

    // bijective XCD swizzle: 3456 = 8 * 432
    int bid0 = blockIdx.x;
    int bid  = (bid0 & 7) * 432 + (bid0 >> 3);
    const int b    = bid / 1728;
    int r          = bid % 1728;
    const int h    = r / 72;  r %= 72;
    const int w0   = r / 3;
    const int dseg = r % 3;
    const int dbase = dseg * 8;
    const int b4   = b * 4;

    const int i_  = l & 15;
    const int tl4 = l >> 4;
    const int d_i = i_ >> 2;
    const int t_i = i_ & 3;
    const int co  = l & 15;

    // ---- per-thread staging site offsets (sign<0 => zero page) ----
    int voff[10];
#pragma unroll
    for (int it = 0; it < 10; ++it) {
        int idx = it * 256 + tid;              // site = p*260 + tt*10 + dd
        int p  = idx / 260;
        int rr = idx - p * 260;
        int tt = rr / 10;
        int dd = rr - tt * 10;
        int hh = h  + p / 3 - 1;
        int ww = w0 + p % 3 - 1;
        int dp = dbase + dd - 1;
        int tp = tt - 1;
        bool valid = ((unsigned)hh < 24u) && ((unsigned)ww < 24u) &&
                     ((unsigned)dp < 24u) && ((unsigned)tp < 24u) &&
                     (idx < NSITE2);
        voff[it] = valid ? (hh * XS3 + ww * XS2 + dp * 24 + tp) * 16 : -1;
    }

    const char* xsb = (const char*)xs;

#define STAGE(K, PB) {                                                         \
    const char* gb = xsb + (size_t)(b4 + (K)) * (size_t)(XS4 * 16);            \
    char* lb = (char*)&xbuf[(PB)][0];                                          \
    _Pragma("unroll")                                                          \
    for (int it = 0; it < 10; ++it) {                                          \
        const char* g = (voff[it] >= 0) ? (gb + voff[it]) : zptr;              \
        __builtin_amdgcn_global_load_lds(                                      \
            (const __attribute__((address_space(1))) void*)g,                  \
            (__attribute__((address_space(3))) void*)(lb + (it * 256 + tid) * 16), \
            16, 0, 0);                                                         \
    } }

    // prologue: stage phase 0 into buf 0
    STAGE(0, 0);

    // ---- per-lane LDS tap offsets and m-tile offsets ----
    int goff[21];
#pragma unroll
    for (int g = 0; g < 21; ++g) {
        int tau  = 4 * g + tl4;
        int teff = tau > 80 ? 80 : tau;
        int p    = teff / 9;
        int r9   = teff - p * 9;
        int kd   = r9 / 3;
        int kt   = r9 - kd * 3;
        goff[g]  = p * 4160 + kt * 160 + kd * 16;   // site stride 16B, tt 160B
    }
    int la[3];
#pragma unroll
    for (int j = 0; j < 3; ++j) {
        int mt = wv * 3 + j;                  // m-tile 0..11
        int dq = mt / 6, tq = mt % 6;
        la[j] = (tq * 4 + t_i) * 160 + (dq * 4 + d_i) * 16;
    }

    f32x4 acc[3];
#pragma unroll
    for (int j = 0; j < 3; ++j) acc[j] = (f32x4){0.f, 0.f, 0.f, 0.f};

    const char* wB = (const char*)wfrag + tl4 * 256 + co * 16;

#pragma unroll
    for (int k = 0; k < 4; ++k) {
        __syncthreads();                       // drains stage(k), frees buf
        if (k < 3) STAGE(k + 1, (k + 1) & 1);  // prefetch next phase

        const char* pw = wB + (k >> 1) * 43008;
        const char* sb = (const char*)&xbuf[k & 1][0];

        if ((k & 1) == 0) {
            // hi phase: xh*wh + xh*wl
#pragma unroll
            for (int g = 0; g < 21; ++g) {
                bfrag wh = *(const bfrag*)(pw + g * 1024);
                bfrag wl = *(const bfrag*)(pw + g * 1024 + 21504);
                const char* ax = sb + goff[g];
                bfrag x0 = *(const bfrag*)(ax + la[0]);
                bfrag x1 = *(const bfrag*)(ax + la[1]);
                bfrag x2 = *(const bfrag*)(ax + la[2]);
                __builtin_amdgcn_s_setprio(1);
                acc[0] = __builtin_amdgcn_mfma_f32_16x16x32_bf16(x0, wh, acc[0], 0, 0, 0);
                acc[1] = __builtin_amdgcn_mfma_f32_16x16x32_bf16(x1, wh, acc[1], 0, 0, 0);
                acc[2] = __builtin_amdgcn_mfma_f32_16x16x32_bf16(x2, wh, acc[2], 0, 0, 0);
                acc[0] = __builtin_amdgcn_mfma_f32_16x16x32_bf16(x0, wl, acc[0], 0, 0, 0);
                acc[1] = __builtin_amdgcn_mfma_f32_16x16x32_bf16(x1, wl, acc[1], 0, 0, 0);
                acc[2] = __builtin_amdgcn_mfma_f32_16x16x32_bf16(x2, wl, acc[2], 0, 0, 0);
                __builtin_amdgcn_s_setprio(0);
            }
        } else {
            // lo phase: xl*wh
#pragma unroll
            for (int g = 0; g < 21; ++g) {
                bfrag wh = *(const bfrag*)(pw + g * 1024);
                const char* ax = sb + goff[g];
                bfrag x0 = *(const bfrag*)(ax + la[0]);
                bfrag x1 = *(const bfrag*)(ax + la[1]);
                bfrag x2 = *(const bfrag*)(ax + la[2]);
                __builtin_amdgcn_s_setprio(1);
                acc[0] = __builtin_amdgcn_mfma_f32_16x16x32_bf16(x0, wh, acc[0], 0, 0, 0);
                acc[1] = __builtin_amdgcn_mfma_f32_16x16x32_bf16(x1, wh, acc[1], 0, 0, 0);
                acc[2] = __builtin_amdgcn_mfma_f32_16x16x32_bf16(x2, wh, acc[2], 0, 0, 0);
                __builtin_amdgcn_s_setprio(0);
            }
        }
    }
#undef STAGE

    // ---- epilogue: row = tl4*4 + reg -> d = dq*4 + tl4, t = tq*4 + reg ----
    const float bv = bias[co];
    const size_t ob = (size_t)(b * 16 + co) * XS4 + h * XS3 + w0 * XS2;
#pragma unroll
    for (int j = 0; j < 3; ++j) {
        int mt = wv * 3 + j;
        int dq = mt / 6, tq = mt % 6;
        int d = dbase + dq * 4 + tl4;
        int t = tq * 4;
        float4 v;
        v.x = acc[j][0] + bv; v.y = acc[j][1] + bv;
        v.z = acc[j][2] + bv; v.w = acc[j][3] + bv;
        *(float4*)&out[ob + d * 24 + t] = v;
    }
}

// ---------------- fallback (in-kernel split, used if ws too small) ----------
__global__ void wsplit_kernel(const float* __restrict__ w,
                              unsigned int* __restrict__ ws) {
    int e = blockIdx.x * 256 + threadIdx.x;
    int ci2 = e & 3;
    int co  = (e >> 2) & 15;
    int t84 = e >> 6;
    int tau = t84 % 84;
    int cs  = t84 / 84;
    int ch  = cs >> 1;
    int s   = cs & 1;
    unsigned int outv = 0u;
    if (tau < 81) {
        unsigned int half[2];
#pragma unroll
        for (int q = 0; q < 2; ++q) {
            int ci = ch * 8 + ci2 * 2 + q;
            union { float f; unsigned u; } v;
            v.f = w[(co * 16 + ci) * 81 + tau];
            unsigned hi = v.u & 0xFFFF0000u;
            union { unsigned u; float f; } hv; hv.u = hi;
            union { float f; unsigned u; } rv; rv.f = v.f - hv.f;
            unsigned lo = rv.u & 0xFFFF0000u;
            half[q] = (s == 0) ? hi : lo;
        }
        outv = (half[0] >> 16) | (half[1] & 0xFFFF0000u);
    }
    ws[e] = outv;
}

__global__ __launch_bounds__(192, 3)
void conv4d_mfma_v1(const float* __restrict__ x,
                    const unsigned short* __restrict__ wfrag,
                    const float* __restrict__ bias,
                    float* __restrict__ out) {
    __shared__ __align__(16) unsigned short xhl[2][1260][8];

    const int tid = threadIdx.x;
    const int l   = tid & 63;

    int bid = blockIdx.x;
    const int b    = bid / 3456;
    int r          = bid % 3456;
    const int h    = r / 144;
    r              = r % 144;
    const int w0   = r / 6;
    const int seg  = r % 6;
    const int dbase = (seg >> 1) * 8, tbase = (seg & 1) * 12;

    const int i_  = l & 15;
    const int tl4 = l >> 4;
    const int d_i = i_ >> 2;
    const int t_i = i_ & 3;
    const int co  = l & 15;

    const int wv  = tid >> 6;
    const int mt0 = wv * 2, mt1 = wv * 2 + 1;
    const int dq0 = mt0 / 3, tq0 = mt0 % 3;
    const int dq1 = mt1 / 3, tq1 = mt1 % 3;
    const int la0 = dq0 * 896 + tq0 * 64 + d_i * 224 + t_i * 16;
    const int la1 = dq1 * 896 + tq1 * 64 + d_i * 224 + t_i * 16;

    f32x4 acc0 = {0.f, 0.f, 0.f, 0.f};
    f32x4 acc1 = {0.f, 0.f, 0.f, 0.f};

    const char* xbase = (const char*)&xhl[0][0][0];
    const char* wB    = (const char*)wfrag + tl4 * 256 + co * 16;

    for (int ch = 0; ch < 2; ++ch) {
        __syncthreads();
        for (int k = 0; k < 7; ++k) {
            int idx = tid + k * 192;
            if (idx < 1260) {
                int p  = idx / 140;
                int rr = idx - p * 140;
                int dd = rr / 14;
                int tt = rr - dd * 14;
                int hh = h  + p / 3 - 1;
                int ww = w0 + p % 3 - 1;
                int dp = dbase + dd - 1;
                int tp = tbase + tt - 1;
                unsigned hib[8], lob[8];
                bool valid = ((unsigned)hh < 24u) && ((unsigned)ww < 24u) &&
                             ((unsigned)dp < 24u) && ((unsigned)tp < 24u);
                if (valid) {
                    int g = b * (16 * XS4) + (ch * 8) * XS4
                          + hh * XS3 + ww * XS2 + dp * 24 + tp;
#pragma unroll
                    for (int c = 0; c < 8; ++c) {
                        union { float f; unsigned u; } v;
                        v.f = x[g + c * XS4];
                        unsigned hi = v.u & 0xFFFF0000u;
                        union { unsigned u; float f; } hv; hv.u = hi;
                        union { float f; unsigned u; } rv2; rv2.f = v.f - hv.f;
                        hib[c] = hi;
                        lob[c] = rv2.u & 0xFFFF0000u;
                    }
                } else {
#pragma unroll
                    for (int c = 0; c < 8; ++c) { hib[c] = 0u; lob[c] = 0u; }
                }
                uint4 ph, pl;
                ph.x = (hib[0] >> 16) | (hib[1] & 0xFFFF0000u);
                ph.y = (hib[2] >> 16) | (hib[3] & 0xFFFF0000u);
                ph.z = (hib[4] >> 16) | (hib[5] & 0xFFFF0000u);
                ph.w = (hib[6] >> 16) | (hib[7] & 0xFFFF0000u);
                pl.x = (lob[0] >> 16) | (lob[1] & 0xFFFF0000u);
                pl.y = (lob[2] >> 16) | (lob[3] & 0xFFFF0000u);
                pl.z = (lob[4] >> 16) | (lob[5] & 0xFFFF0000u);
                pl.w = (lob[6] >> 16) | (lob[7] & 0xFFFF0000u);
                *(uint4*)((char*)&xhl[0][0][0] + idx * 16)         = ph;
                *(uint4*)((char*)&xhl[0][0][0] + 20160 + idx * 16) = pl;
            }
        }
        __syncthreads();

        const char* pw = wB + ch * 43008;
#pragma unroll
        for (int g = 0; g < 21; ++g) {
            bfrag whf = *(const bfrag*)(pw + g * 1024);
            bfrag wlf = *(const bfrag*)(pw + g * 1024 + 21504);

            int tau  = 4 * g + tl4;
            int teff = tau > 80 ? 80 : tau;
            int p    = teff / 9;
            int r9   = teff - p * 9;
            int kd   = r9 / 3;
            int kt   = r9 - kd * 3;
            int aoff = p * 2240 + kd * 224 + kt * 16;

            const char* ax = xbase + aoff;
            bfrag xh0 = *(const bfrag*)(ax + la0);
            bfrag xl0 = *(const bfrag*)(ax + la0 + 20160);
            bfrag xh1 = *(const bfrag*)(ax + la1);
            bfrag xl1 = *(const bfrag*)(ax + la1 + 20160);

            acc0 = __builtin_amdgcn_mfma_f32_16x16x32_bf16(xh0, whf, acc0, 0, 0, 0);
            acc1 = __builtin_amdgcn_mfma_f32_16x16x32_bf16(xh1, whf, acc1, 0, 0, 0);
            acc0 = __builtin_amdgcn_mfma_f32_16x16x32_bf16(xh0, wlf, acc0, 0, 0, 0);
            acc1 = __builtin_amdgcn_mfma_f32_16x16x32_bf16(xh1, wlf, acc1, 0, 0, 0);
            acc0 = __builtin_amdgcn_mfma_f32_16x16x32_bf16(xl0, whf, acc0, 0, 0, 0);
            acc1 = __builtin_amdgcn_mfma_f32_16x16x32_bf16(xl1, whf, acc1, 0, 0, 0);
        }
    }

    const float bv = bias[co];
    const int ob = (b * 16 + co) * XS4 + h * XS3 + w0 * XS2;
    {
        int d = dbase + dq0 * 4 + tl4;
        int t = tbase + tq0 * 4;
        float4 v;
        v.x = acc0[0] + bv; v.y = acc0[1] + bv;
        v.z = acc0[2] + bv; v.w = acc0[3] + bv;
        *(float4*)&out[ob + d * 24 + t] = v;
    }
    {
        int d = dbase + dq1 * 4 + tl4;
        int t = tbase + tq1 * 4;
        float4 v;
        v.x = acc1[0] + bv; v.y = acc1[1] + bv;
        v.z = acc1[2] + bv; v.w = acc1[3] + bv;
        *(float4*)&out[ob + d * 24 + t] = v;
    }
}

extern "C" void kernel_launch(void* const* d_in, const int* in_sizes, int n_in,
                              void* d_out, int out_size, void* d_ws, size_t ws_size,
                              hipStream_t stream) {
    const float* x    = (const float*)d_in[0];
    const float* w    = (const float*)d_in[1];
    const float* bias = (const float*)d_in[2];
    float* out        = (float*)d_out;
    char* ws          = (char*)d_ws;
    unsigned* wfrag   = (unsigned*)ws;

    if (ws_size >= WS_NEED) {
        unsigned short* xsq = (unsigned short*)(ws + WS_XS);
        presplit_kernel<<<84 + 5184, 256, 0, stream>>>(x, w, wfrag, xsq);
        conv4d_pipe<<<3456, 256, 0, stream>>>(
            xsq, (const unsigned short*)wfrag, ws + WS_ZERO, bias, out);
    } else {
        wsplit_kernel<<<84, 256, 0, stream>>>(w, wfrag);
        conv4d_mfma_v1<<<6912, 192, 0, stream>>>(
            x, (const unsigned short*)wfrag, bias, out);
    }
}